// Round 10
// baseline (642.345 us; speedup 1.0000x reference)
//
#include <hip/hip_runtime.h>

// GIN encoder: 3 x [CSR gather-agg bf16, fused MFMA MLP(128->128->D), BN-stats] + segmented mean-pool
// N=100000 nodes, E=1600000 edges, G=128 graphs.
// R10: fused_mlp slimmed for occupancy: no sWa LDS stage (Wa frags from L2), 18 KB LDS
//      -> ~5 blocks/CU (was 3 at 50 KB); 1563 one-tile blocks (no grid-stride tail);
//      wave-reduced stats (shfl_xor across quads). Gathers at their 3.5 TB/s fabric ceiling.

#define N_NODES 100000
#define N_EDGES 1600000
#define N_GRAPHS 128
#define BN_EPS 1e-5f
#define POOL_CHUNK 400
#define POOL_BLOCKS ((N_NODES + POOL_CHUNK - 1) / POOL_CHUNK)  // 250
#define NBUCKETS ((N_NODES + 511) / 512)                       // 196
#define PSC_CHUNK 4096
#define PSC_BLOCKS ((N_EDGES + PSC_CHUNK - 1) / PSC_CHUNK)     // 391
#define PSC_CAP 10240                                          // slots per bucket (E[cnt]=8192)
#define MLP_TILES ((N_NODES + 63) / 64)                        // 1563
#define INV_N (1.0f / (float)N_NODES)

typedef __attribute__((ext_vector_type(8))) short bf16x8;
typedef __attribute__((ext_vector_type(4))) float f32x4;

// ---------------------------------------------------------------- bf16 helpers
__device__ __forceinline__ unsigned short rne16(float f) {
  unsigned u = __float_as_uint(f);
  u += 0x7fffu + ((u >> 16) & 1u);
  return (unsigned short)(u >> 16);
}
__device__ __forceinline__ unsigned pack2(float lo, float hi) {
  unsigned a = __float_as_uint(lo); a += 0x7fffu + ((a >> 16) & 1u);
  unsigned b = __float_as_uint(hi); b += 0x7fffu + ((b >> 16) & 1u);
  return (a >> 16) | (b & 0xffff0000u);
}
__device__ __forceinline__ void bf2_to_f32(unsigned u, float& lo, float& hi) {
  lo = __uint_as_float(u << 16);
  hi = __uint_as_float(u & 0xffff0000u);
}
__device__ __forceinline__ void bf8_to_f32(uint4 u, float* f) {
  bf2_to_f32(u.x, f[0], f[1]);
  bf2_to_f32(u.y, f[2], f[3]);
  bf2_to_f32(u.z, f[4], f[5]);
  bf2_to_f32(u.w, f[6], f[7]);
}

// ---------------------------------------------------------------- weight prep (all 6 in one launch)
// W(K=128 x N fp32) -> B-operand frag-ordered bf16:
// flat = ((ntile*4 + kchunk)*64 + lane)*8 + j ; k = kchunk*32 + (lane>>4)*8 + j ; n = ntile*16 + (lane&15)
struct WPArgs {
  const float* w[6];
  unsigned short* o[6];
};
__global__ __launch_bounds__(256) void wprep_all_kernel(WPArgs wp) {
  int blk = blockIdx.x;
  int seg = (blk < 320) ? (blk >> 6) : 5;
  int base = (seg < 5) ? (seg << 6) : 320;
  int N = (seg == 5) ? 64 : 128;
  int f = (blk - base) * 256 + threadIdx.x;
  if (f >= 128 * N) return;
  int j = f & 7;
  int lane = (f >> 3) & 63;
  int t = f >> 9;
  int kchunk = t & 3, ntile = t >> 2;
  int k = kchunk * 32 + (lane >> 4) * 8 + j;
  int n = ntile * 16 + (lane & 15);
  wp.o[seg][f] = rne16(wp.w[seg][k * N + n]);
}

// ---------------------------------------------------------------- CSR build (3 kernels)
__global__ __launch_bounds__(256) void pscatter_kernel(const int* __restrict__ src,
                                                       const int* __restrict__ dst,
                                                       int* __restrict__ cnt,
                                                       unsigned* __restrict__ pairs) {
  __shared__ int hist[NBUCKETS];
  __shared__ int base[NBUCKETS];
  int tid = threadIdx.x;
  for (int i = tid; i < NBUCKETS; i += 256) hist[i] = 0;
  __syncthreads();
  int e0 = blockIdx.x * PSC_CHUNK;
  int e1 = min(e0 + PSC_CHUNK, N_EDGES);
  for (int e = e0 + tid; e < e1; e += 256) atomicAdd(&hist[dst[e] >> 9], 1);
  __syncthreads();
  for (int i = tid; i < NBUCKETS; i += 256) {
    int c = hist[i];
    base[i] = c ? atomicAdd(&cnt[i], c) : 0;
    hist[i] = 0;
  }
  __syncthreads();
  for (int e = e0 + tid; e < e1; e += 256) {
    int d = dst[e];
    int b = d >> 9;
    int slot = base[b] + atomicAdd(&hist[b], 1);
    if (slot < PSC_CAP)
      pairs[(size_t)b * PSC_CAP + slot] = ((unsigned)src[e] << 9) | (unsigned)(d & 511);
  }
}

__global__ __launch_bounds__(256) void bscan_kernel(const int* __restrict__ cnt,
                                                    int* __restrict__ boff,
                                                    int* __restrict__ row_ptr) {
  __shared__ int tmp[256];
  int tid = threadIdx.x;
  int c = (tid < NBUCKETS) ? cnt[tid] : 0;
  tmp[tid] = c;
  __syncthreads();
  for (int off = 1; off < 256; off <<= 1) {
    int t = (tid >= off) ? tmp[tid - off] : 0;
    __syncthreads();
    tmp[tid] += t;
    __syncthreads();
  }
  if (tid < NBUCKETS) boff[tid] = tmp[tid] - c;
  if (tid == 0) row_ptr[N_NODES] = N_EDGES;
}

__global__ __launch_bounds__(256) void bbuild_kernel(const unsigned* __restrict__ pairs,
                                                     const int* __restrict__ cnt,
                                                     const int* __restrict__ boff,
                                                     int* __restrict__ row_ptr,
                                                     int* __restrict__ adj) {
  __shared__ unsigned spairs[PSC_CAP];  // 40 KB
  __shared__ int h[512];
  __shared__ int cur[512];
  __shared__ int tmp[256];
  int tid = threadIdx.x, b = blockIdx.x;
  int c = min(cnt[b], PSC_CAP);
  int p0 = boff[b];
  const unsigned* gp = pairs + (size_t)b * PSC_CAP;
  for (int p = tid; p < c; p += 256) spairs[p] = gp[p];
  h[tid] = 0;
  h[tid + 256] = 0;
  __syncthreads();
  for (int p = tid; p < c; p += 256) atomicAdd(&h[spairs[p] & 511u], 1);
  __syncthreads();
  int a0 = h[2 * tid], a1 = h[2 * tid + 1];
  int s = a0 + a1;
  tmp[tid] = s;
  __syncthreads();
  for (int off = 1; off < 256; off <<= 1) {
    int t = (tid >= off) ? tmp[tid - off] : 0;
    __syncthreads();
    tmp[tid] += t;
    __syncthreads();
  }
  int excl = tmp[tid] - s;
  int n0 = b << 9;
  if (n0 + 2 * tid < N_NODES) row_ptr[n0 + 2 * tid] = p0 + excl;
  if (n0 + 2 * tid + 1 < N_NODES) row_ptr[n0 + 2 * tid + 1] = p0 + excl + a0;
  cur[2 * tid] = p0 + excl;
  cur[2 * tid + 1] = p0 + excl + a0;
  __syncthreads();
  for (int p = tid; p < c; p += 256) {
    unsigned pr = spairs[p];
    int pos = atomicAdd(&cur[pr & 511u], 1);
    adj[pos] = (int)(pr >> 9);
  }
}

// ---------------------------------------------------------------- gather agg, layer 0 (fp32 in, bf16 out)
__global__ __launch_bounds__(256) void gather_l0_kernel(
    const float* __restrict__ in, const int* __restrict__ row_ptr,
    const int* __restrict__ adj, unsigned short* __restrict__ agg) {
  int gid = blockIdx.x * 256 + threadIdx.x;
  int n = gid >> 4;
  if (n >= N_NODES) return;
  int c8 = gid & 15;
  float acc[8];
  {
    const float4* p = (const float4*)(in + (size_t)n * 128) + c8 * 2;
    float4 a = p[0], b = p[1];
    acc[0] = a.x; acc[1] = a.y; acc[2] = a.z; acc[3] = a.w;
    acc[4] = b.x; acc[5] = b.y; acc[6] = b.z; acc[7] = b.w;
  }
  int beg = row_ptr[n], end = row_ptr[n + 1];
  for (int k = beg; k < end; ++k) {
    const float4* p = (const float4*)(in + (size_t)adj[k] * 128) + c8 * 2;
    float4 a = p[0], b = p[1];
    acc[0] += a.x; acc[1] += a.y; acc[2] += a.z; acc[3] += a.w;
    acc[4] += b.x; acc[5] += b.y; acc[6] += b.z; acc[7] += b.w;
  }
  uint4 o;
  o.x = pack2(acc[0], acc[1]); o.y = pack2(acc[2], acc[3]);
  o.z = pack2(acc[4], acc[5]); o.w = pack2(acc[6], acc[7]);
  ((uint4*)(agg + (size_t)n * 128))[c8] = o;
}

// ---------------------------------------------------------------- gather agg, layers 1/2
// bf16 in/out; BN scale/shift computed in-kernel from raw stats (sum | sumsq) + g + be.
__global__ __launch_bounds__(256) void gather_ln_kernel(
    const unsigned short* __restrict__ in, const float* __restrict__ stats,
    const float* __restrict__ g, const float* __restrict__ be,
    const int* __restrict__ row_ptr, const int* __restrict__ adj,
    unsigned short* __restrict__ agg) {
  int gid = blockIdx.x * 256 + threadIdx.x;
  int n = gid >> 4;
  if (n >= N_NODES) return;
  int c8 = gid & 15;
  float sc[8], sh[8];
#pragma unroll
  for (int j = 0; j < 8; ++j) {
    int col = c8 * 8 + j;
    float mean = stats[col] * INV_N;
    float var = stats[128 + col] * INV_N - mean * mean;
    float s = g[col] * rsqrtf(var + BN_EPS);
    sc[j] = s;
    sh[j] = be[col] - mean * s;
  }
  float acc[8];
  auto addf = [&](const float* f) {
#pragma unroll
    for (int j = 0; j < 8; ++j) acc[j] += fmaxf(fmaf(f[j], sc[j], sh[j]), 0.f);
  };
  int beg = row_ptr[n], end = row_ptr[n + 1];
  {
    uint4 u = ((const uint4*)(in + (size_t)n * 128))[c8];
    float f[8];
    bf8_to_f32(u, f);
#pragma unroll
    for (int j = 0; j < 8; ++j) acc[j] = fmaxf(fmaf(f[j], sc[j], sh[j]), 0.f);
  }
  int k = beg;
  for (; k + 4 <= end; k += 4) {
    int s0 = adj[k], s1 = adj[k + 1], s2 = adj[k + 2], s3 = adj[k + 3];
    uint4 u0 = ((const uint4*)(in + (size_t)s0 * 128))[c8];
    uint4 u1 = ((const uint4*)(in + (size_t)s1 * 128))[c8];
    uint4 u2 = ((const uint4*)(in + (size_t)s2 * 128))[c8];
    uint4 u3 = ((const uint4*)(in + (size_t)s3 * 128))[c8];
    float f[8];
    bf8_to_f32(u0, f); addf(f);
    bf8_to_f32(u1, f); addf(f);
    bf8_to_f32(u2, f); addf(f);
    bf8_to_f32(u3, f); addf(f);
  }
  for (; k < end; ++k) {
    uint4 u = ((const uint4*)(in + (size_t)adj[k] * 128))[c8];
    float f[8];
    bf8_to_f32(u, f);
    addf(f);
  }
  uint4 o;
  o.x = pack2(acc[0], acc[1]); o.y = pack2(acc[2], acc[3]);
  o.z = pack2(acc[4], acc[5]); o.w = pack2(acc[6], acc[7]);
  ((uint4*)(agg + (size_t)n * 128))[c8] = o;
}

// ---------------------------------------------------------------- fused MLP: O = mlp2(relu(mlp1(A)))
// One 64-row tile per block. Wa AND Wb fragments read from L2 (no LDS weight stage ->
// 18 KB LDS, ~5 blocks/CU). GEMM1 -> per-wave XOR-swizzled LDS bounce -> GEMM2.
// Stats wave-reduced (shfl_xor across quads) -> LDS -> one global atomic pass.
template <int N2>
__global__ __launch_bounds__(256) void fused_mlp_kernel(
    const unsigned short* __restrict__ A, const unsigned short* __restrict__ Wfa,
    const unsigned short* __restrict__ Wfb, const float* __restrict__ ba,
    const float* __restrict__ bb, unsigned short* __restrict__ O,
    float* __restrict__ gstats, int M) {
  constexpr int NT2 = N2 / 16;
  __shared__ unsigned short sH1[4][16 * 128];  // 16 KB, per-wave bounce
  __shared__ float sB[256];                    // ba(128) | bb(<=128)
  __shared__ float sSt[2 * N2];

  int tid = threadIdx.x;
  if (tid < 128) sB[tid] = ba[tid];
  else if (tid - 128 < N2) sB[tid] = bb[tid - 128];
  for (int i = tid; i < 2 * N2; i += 256) sSt[i] = 0.f;
  __syncthreads();

  int lane = tid & 63, wave = tid >> 6;
  int m16 = lane & 15, quad = lane >> 4;
  unsigned short* h1 = &sH1[wave][0];
  const bf16x8* Wfa8 = (const bf16x8*)Wfa;
  const bf16x8* Wfb8 = (const bf16x8*)Wfb;

  int row0 = blockIdx.x * 64 + wave * 16;
  int row = row0 + m16;

  bf16x8 a[4];
  if (row < M) {
    const bf16x8* Ar = (const bf16x8*)(A + (size_t)row * 128);
#pragma unroll
    for (int kc = 0; kc < 4; ++kc) a[kc] = Ar[kc * 4 + quad];
  } else {
#pragma unroll
    for (int kc = 0; kc < 4; ++kc)
#pragma unroll
      for (int j = 0; j < 8; ++j) a[kc][j] = 0;
  }

  f32x4 acc2[NT2];
#pragma unroll
  for (int nt = 0; nt < NT2; ++nt) {
    float bv = sB[128 + nt * 16 + m16];
#pragma unroll
    for (int r = 0; r < 4; ++r) acc2[nt][r] = bv;
  }

#pragma unroll
  for (int kc2 = 0; kc2 < 4; ++kc2) {
    bf16x8 wb[NT2];
#pragma unroll
    for (int nt = 0; nt < NT2; ++nt) wb[nt] = Wfb8[(nt * 4 + kc2) * 64 + lane];

#pragma unroll
    for (int t2 = 0; t2 < 2; ++t2) {
      int n1t = 2 * kc2 + t2;
      float bv = sB[n1t * 16 + m16];
      f32x4 acc1 = {bv, bv, bv, bv};
#pragma unroll
      for (int kc = 0; kc < 4; ++kc)
        acc1 = __builtin_amdgcn_mfma_f32_16x16x32_bf16(
            a[kc], Wfa8[(n1t * 4 + kc) * 64 + lane], acc1, 0, 0, 0);
      int n1 = n1t * 16 + m16;
      int c = n1 >> 3;
#pragma unroll
      for (int r = 0; r < 4; ++r) {
        int mrow = quad * 4 + r;
        h1[mrow * 128 + (((c ^ mrow) & 15) << 3) + (n1 & 7)] =
            rne16(fmaxf(acc1[r], 0.f));
      }
    }
    int cR = kc2 * 4 + quad;
    bf16x8 hf = *(const bf16x8*)&h1[m16 * 128 + (((cR ^ m16) & 15) << 3)];
#pragma unroll
    for (int nt = 0; nt < NT2; ++nt)
      acc2[nt] = __builtin_amdgcn_mfma_f32_16x16x32_bf16(hf, wb[nt], acc2[nt], 0, 0, 0);
  }

#pragma unroll
  for (int nt = 0; nt < NT2; ++nt) {
    float s = 0.f, ss = 0.f;
#pragma unroll
    for (int r = 0; r < 4; ++r) {
      int grow = row0 + quad * 4 + r;
      if (grow < M) {
        float v = acc2[nt][r];
        s += v;
        ss += v * v;
        O[(size_t)grow * N2 + nt * 16 + m16] = rne16(v);
      }
    }
    s += __shfl_xor(s, 16);
    s += __shfl_xor(s, 32);
    ss += __shfl_xor(ss, 16);
    ss += __shfl_xor(ss, 32);
    if (quad == 0) {
      atomicAdd(&sSt[nt * 16 + m16], s);
      atomicAdd(&sSt[N2 + nt * 16 + m16], ss);
    }
  }
  __syncthreads();
  for (int i = tid; i < 2 * N2; i += 256) atomicAdd(&gstats[i], sSt[i]);
}

// ---------------------------------------------------------------- segmented mean pool
// bf16 in; BN params computed in-kernel from raw stats (64 cols) + g + be.
__global__ __launch_bounds__(256) void pool_seg_kernel(
    const unsigned short* __restrict__ h, const float* __restrict__ stats,
    const float* __restrict__ g, const float* __restrict__ be,
    const int* __restrict__ batch, float* __restrict__ sums) {
  __shared__ float sacc[N_GRAPHS * 64];
  int tid = threadIdx.x;
  for (int i = tid; i < N_GRAPHS * 64; i += 256) sacc[i] = 0.f;

  int base = blockIdx.x * POOL_CHUNK;
  int last = min(base + POOL_CHUNK, N_NODES) - 1;
  int c4 = tid & 15;
  int r = tid >> 4;
  float4 sc, sh;
  {
    float m0 = stats[c4 * 4 + 0] * INV_N, m1 = stats[c4 * 4 + 1] * INV_N;
    float m2 = stats[c4 * 4 + 2] * INV_N, m3 = stats[c4 * 4 + 3] * INV_N;
    sc.x = g[c4 * 4 + 0] * rsqrtf(stats[64 + c4 * 4 + 0] * INV_N - m0 * m0 + BN_EPS);
    sc.y = g[c4 * 4 + 1] * rsqrtf(stats[64 + c4 * 4 + 1] * INV_N - m1 * m1 + BN_EPS);
    sc.z = g[c4 * 4 + 2] * rsqrtf(stats[64 + c4 * 4 + 2] * INV_N - m2 * m2 + BN_EPS);
    sc.w = g[c4 * 4 + 3] * rsqrtf(stats[64 + c4 * 4 + 3] * INV_N - m3 * m3 + BN_EPS);
    sh.x = be[c4 * 4 + 0] - m0 * sc.x;
    sh.y = be[c4 * 4 + 1] - m1 * sc.y;
    sh.z = be[c4 * 4 + 2] - m2 * sc.z;
    sh.w = be[c4 * 4 + 3] - m3 * sc.w;
  }
  __syncthreads();

  float4 acc = make_float4(0.f, 0.f, 0.f, 0.f);
  int gcur = -1;
#pragma unroll 1
  for (int j = 0; j < POOL_CHUNK / 16; ++j) {
    int node = base + j * 16 + r;
    if (node >= N_NODES) break;
    int gg = batch[node];
    if (gg != gcur) {
      if (gcur >= 0) {
        float* p = &sacc[gcur * 64 + c4 * 4];
        atomicAdd(p + 0, acc.x); atomicAdd(p + 1, acc.y);
        atomicAdd(p + 2, acc.z); atomicAdd(p + 3, acc.w);
      }
      gcur = gg;
      acc = make_float4(0.f, 0.f, 0.f, 0.f);
    }
    uint2 u = ((const uint2*)(h + (size_t)node * 64))[c4];
    float f0, f1, f2, f3;
    bf2_to_f32(u.x, f0, f1);
    bf2_to_f32(u.y, f2, f3);
    acc.x += fmaxf(fmaf(f0, sc.x, sh.x), 0.f);
    acc.y += fmaxf(fmaf(f1, sc.y, sh.y), 0.f);
    acc.z += fmaxf(fmaf(f2, sc.z, sh.z), 0.f);
    acc.w += fmaxf(fmaf(f3, sc.w, sh.w), 0.f);
  }
  if (gcur >= 0) {
    float* p = &sacc[gcur * 64 + c4 * 4];
    atomicAdd(p + 0, acc.x); atomicAdd(p + 1, acc.y);
    atomicAdd(p + 2, acc.z); atomicAdd(p + 3, acc.w);
  }
  __syncthreads();

  int gmin = batch[base];
  int gmax = batch[last];
  for (int gg = gmin; gg <= gmax; ++gg)
    for (int i = tid; i < 64; i += 256)
      atomicAdd(&sums[gg * 64 + i], sacc[gg * 64 + i]);
}

// ---------------------------------------------------------------- divide by counts (binary search)
__global__ __launch_bounds__(256) void div_kernel(const float* __restrict__ sums,
                                                  const int* __restrict__ batch,
                                                  float* __restrict__ out) {
  int i = blockIdx.x * blockDim.x + threadIdx.x;
  if (i >= N_GRAPHS * 64) return;
  int g = i >> 6;
  int lo = 0, hi = N_NODES;
  while (lo < hi) { int m = (lo + hi) >> 1; if (batch[m] < g) lo = m + 1; else hi = m; }
  int lb = lo;
  lo = 0; hi = N_NODES;
  while (lo < hi) { int m = (lo + hi) >> 1; if (batch[m] <= g) lo = m + 1; else hi = m; }
  float cnt = (float)(lo - lb);
  out[i] = sums[i] / fmaxf(cnt, 1.0f);
}

// ---------------------------------------------------------------- launch
extern "C" void kernel_launch(void* const* d_in, const int* in_sizes, int n_in,
                              void* d_out, int out_size, void* d_ws, size_t ws_size,
                              hipStream_t stream) {
  const float* x = (const float*)d_in[0];
  const int* edge_index = (const int*)d_in[1];
  const int* batch = (const int*)d_in[2];
  const int* src = edge_index;
  const int* dst = edge_index + N_EDGES;

  const float* wa[3] = {(const float*)d_in[3], (const float*)d_in[9],  (const float*)d_in[15]};
  const float* ba[3] = {(const float*)d_in[4], (const float*)d_in[10], (const float*)d_in[16]};
  const float* wb[3] = {(const float*)d_in[5], (const float*)d_in[11], (const float*)d_in[17]};
  const float* bb[3] = {(const float*)d_in[6], (const float*)d_in[12], (const float*)d_in[18]};
  const float* gg[3] = {(const float*)d_in[7], (const float*)d_in[13], (const float*)d_in[19]};
  const float* be[3] = {(const float*)d_in[8], (const float*)d_in[14], (const float*)d_in[20]};

  // -------- workspace layout --------
  float* stats0 = (float*)d_ws;   // [sum(128)|sumsq(128)|pad(256)]
  float* stats1 = stats0 + 512;
  float* stats2 = stats1 + 512;   // [sum(64)|sumsq(64)|pad(128)]
  float* psums = stats2 + 256;    // 8192
  int* cnt = (int*)(psums + (size_t)N_GRAPHS * 64);  // 256, zeroed with floats
  int* boff = cnt + 256;                              // 256
  int* row_ptr = boff + 256;                          // 100004
  int* adj = row_ptr + 100004;
  unsigned* pairs = (unsigned*)(adj + N_EDGES);       // NBUCKETS*PSC_CAP
  unsigned short* b0 = (unsigned short*)(pairs + (size_t)NBUCKETS * PSC_CAP);
  unsigned short* b1 = b0 + (size_t)N_NODES * 128;
  unsigned short* wf0 = b1 + (size_t)N_NODES * 128;
  unsigned short* wf[6];
  for (int i = 0; i < 6; ++i) wf[i] = wf0 + (size_t)i * 16384;
  size_t needed = (size_t)((char*)(wf0 + 6 * 16384) - (char*)d_ws);
  if (ws_size < needed) return;

  hipMemsetAsync(stats0, 0, 9472 * 4 + 256 * 4, stream);

  WPArgs wp;
  wp.w[0] = wa[0]; wp.w[1] = wb[0]; wp.w[2] = wa[1];
  wp.w[3] = wb[1]; wp.w[4] = wa[2]; wp.w[5] = wb[2];
  for (int i = 0; i < 6; ++i) wp.o[i] = wf[i];
  wprep_all_kernel<<<352, 256, 0, stream>>>(wp);

  pscatter_kernel<<<PSC_BLOCKS, 256, 0, stream>>>(src, dst, cnt, pairs);
  bscan_kernel<<<1, 256, 0, stream>>>(cnt, boff, row_ptr);
  bbuild_kernel<<<NBUCKETS, 256, 0, stream>>>(pairs, cnt, boff, row_ptr, adj);

  const int gather_blocks = (N_NODES * 16 + 255) / 256;

  // ---- layer 0: gather(x fp32) -> b0 ; fused MLP b0 -> b1 (stats0)
  gather_l0_kernel<<<gather_blocks, 256, 0, stream>>>(x, row_ptr, adj, b0);
  fused_mlp_kernel<128><<<MLP_TILES, 256, 0, stream>>>(
      b0, wf[0], wf[1], ba[0], bb[0], b1, stats0, N_NODES);

  // ---- layer 1: gather(b1, BN0 from raw stats0) -> b0 ; fused MLP b0 -> b1 (stats1)
  gather_ln_kernel<<<gather_blocks, 256, 0, stream>>>(b1, stats0, gg[0], be[0],
                                                      row_ptr, adj, b0);
  fused_mlp_kernel<128><<<MLP_TILES, 256, 0, stream>>>(
      b0, wf[2], wf[3], ba[1], bb[1], b1, stats1, N_NODES);

  // ---- layer 2: gather(b1, BN1 from raw stats1) -> b0 ; fused MLP b0 -> b1 (N2=64, stats2)
  gather_ln_kernel<<<gather_blocks, 256, 0, stream>>>(b1, stats1, gg[1], be[1],
                                                      row_ptr, adj, b0);
  fused_mlp_kernel<64><<<MLP_TILES, 256, 0, stream>>>(
      b0, wf[4], wf[5], ba[2], bb[2], b1, stats2, N_NODES);

  // ---- pool (BN2 computed in-kernel) + divide
  pool_seg_kernel<<<POOL_BLOCKS, 256, 0, stream>>>(b1, stats2, gg[2], be[2], batch, psums);
  div_kernel<<<32, 256, 0, stream>>>(psums, batch, (float*)d_out);
}

// Round 11
// 526.149 us; speedup vs baseline: 1.2208x; 1.2208x over previous
//
#include <hip/hip_runtime.h>

// GIN encoder: 3 x [CSR gather-agg (fp8 neighbors, bf16 self), fused MFMA MLP, BN-stats] + pool
// N=100000 nodes, E=1600000 edges, G=128 graphs.
// R11: decisive fabric experiment — neighbor rows in fp8-e4m3 (128 B/row, HW cvt decode),
//      self term + MLP path stay bf16/fp32. fused_mlp (R9 best-measured variant) additionally
//      emits the fp8 copy. If the gather is byte-bound at ~3.4 TB/s this halves it; if
//      edge-transaction-bound it's flat and the ceiling is established.

#define N_NODES 100000
#define N_EDGES 1600000
#define N_GRAPHS 128
#define BN_EPS 1e-5f
#define POOL_CHUNK 400
#define POOL_BLOCKS ((N_NODES + POOL_CHUNK - 1) / POOL_CHUNK)  // 250
#define NBUCKETS ((N_NODES + 511) / 512)                       // 196
#define PSC_CHUNK 4096
#define PSC_BLOCKS ((N_EDGES + PSC_CHUNK - 1) / PSC_CHUNK)     // 391
#define PSC_CAP 10240
#define MLP_TILES ((N_NODES + 63) / 64)                        // 1563
#define INV_N (1.0f / (float)N_NODES)

typedef __attribute__((ext_vector_type(8))) short bf16x8;
typedef __attribute__((ext_vector_type(4))) float f32x4;
typedef __attribute__((ext_vector_type(2))) float v2f;

// ---------------------------------------------------------------- bf16 helpers
__device__ __forceinline__ unsigned short rne16(float f) {
  unsigned u = __float_as_uint(f);
  u += 0x7fffu + ((u >> 16) & 1u);
  return (unsigned short)(u >> 16);
}
__device__ __forceinline__ unsigned pack2(float lo, float hi) {
  unsigned a = __float_as_uint(lo); a += 0x7fffu + ((a >> 16) & 1u);
  unsigned b = __float_as_uint(hi); b += 0x7fffu + ((b >> 16) & 1u);
  return (a >> 16) | (b & 0xffff0000u);
}
__device__ __forceinline__ void bf2_to_f32(unsigned u, float& lo, float& hi) {
  lo = __uint_as_float(u << 16);
  hi = __uint_as_float(u & 0xffff0000u);
}
__device__ __forceinline__ void bf8_to_f32(uint4 u, float* f) {
  bf2_to_f32(u.x, f[0], f[1]);
  bf2_to_f32(u.y, f[2], f[3]);
  bf2_to_f32(u.z, f[4], f[5]);
  bf2_to_f32(u.w, f[6], f[7]);
}

// ---------------------------------------------------------------- fp8 e4m3 helpers
__device__ __forceinline__ void fp8x4_to_f32(unsigned w, float* f) {
#if __has_builtin(__builtin_amdgcn_cvt_pk_f32_fp8)
  v2f a = __builtin_amdgcn_cvt_pk_f32_fp8(w, false);
  v2f b = __builtin_amdgcn_cvt_pk_f32_fp8(w, true);
  f[0] = a.x; f[1] = a.y; f[2] = b.x; f[3] = b.y;
#else
#pragma unroll
  for (int i = 0; i < 4; ++i) {
    unsigned v = (w >> (8 * i)) & 0xffu;
    unsigned s = v >> 7, e = (v >> 3) & 15u, m = v & 7u;
    float r;
    if (e) r = __uint_as_float((s << 31) | ((e + 120u) << 23) | (m << 20));
    else { r = (float)m * 0.001953125f; if (s) r = -r; }
    f[i] = r;
  }
#endif
}
__device__ __forceinline__ unsigned char f32_to_fp8(float v) {
#if __has_builtin(__builtin_amdgcn_cvt_pk_fp8_f32)
  return (unsigned char)(__builtin_amdgcn_cvt_pk_fp8_f32(v, v, 0, false) & 0xff);
#else
  unsigned u = __float_as_uint(v);
  unsigned s = (u >> 31) << 7;
  float av = __uint_as_float(u & 0x7fffffffu);
  if (!(av >= 0.015625f)) {
    int m = (int)(av * 512.f + 0.5f);
    return (unsigned char)(s | (m > 8 ? 8 : m));
  }
  if (av > 448.f) av = 448.f;
  unsigned b = __float_as_uint(av);
  b += 0x7ffffu + ((b >> 20) & 1u);
  unsigned e = (b >> 23) - 120u;
  unsigned m = (b >> 20) & 7u;
  if (e > 15u) { e = 15u; m = 6u; }
  if (e == 15u && m == 7u) m = 6u;
  return (unsigned char)(s | (e << 3) | m);
#endif
}

// ---------------------------------------------------------------- x -> fp8 copy (8 elems/thread)
__global__ __launch_bounds__(256) void f2f8_kernel(const float* __restrict__ x,
                                                   unsigned char* __restrict__ x8, int total8) {
  int i = blockIdx.x * 256 + threadIdx.x;
  if (i >= total8) return;
  const float4* p = (const float4*)x + (size_t)i * 2;
  float4 a = p[0], b = p[1];
  uint2 o;
#if __has_builtin(__builtin_amdgcn_cvt_pk_fp8_f32)
  unsigned w0 = __builtin_amdgcn_cvt_pk_fp8_f32(a.x, a.y, 0, false);
  w0 = __builtin_amdgcn_cvt_pk_fp8_f32(a.z, a.w, w0, true);
  unsigned w1 = __builtin_amdgcn_cvt_pk_fp8_f32(b.x, b.y, 0, false);
  w1 = __builtin_amdgcn_cvt_pk_fp8_f32(b.z, b.w, w1, true);
  o.x = w0; o.y = w1;
#else
  o.x = (unsigned)f32_to_fp8(a.x) | ((unsigned)f32_to_fp8(a.y) << 8) |
        ((unsigned)f32_to_fp8(a.z) << 16) | ((unsigned)f32_to_fp8(a.w) << 24);
  o.y = (unsigned)f32_to_fp8(b.x) | ((unsigned)f32_to_fp8(b.y) << 8) |
        ((unsigned)f32_to_fp8(b.z) << 16) | ((unsigned)f32_to_fp8(b.w) << 24);
#endif
  ((uint2*)x8)[i] = o;
}

// ---------------------------------------------------------------- weight prep (all 6 in one launch)
struct WPArgs {
  const float* w[6];
  unsigned short* o[6];
};
__global__ __launch_bounds__(256) void wprep_all_kernel(WPArgs wp) {
  int blk = blockIdx.x;
  int seg = (blk < 320) ? (blk >> 6) : 5;
  int base = (seg < 5) ? (seg << 6) : 320;
  int N = (seg == 5) ? 64 : 128;
  int f = (blk - base) * 256 + threadIdx.x;
  if (f >= 128 * N) return;
  int j = f & 7;
  int lane = (f >> 3) & 63;
  int t = f >> 9;
  int kchunk = t & 3, ntile = t >> 2;
  int k = kchunk * 32 + (lane >> 4) * 8 + j;
  int n = ntile * 16 + (lane & 15);
  wp.o[seg][f] = rne16(wp.w[seg][k * N + n]);
}

// ---------------------------------------------------------------- CSR build (3 kernels)
__global__ __launch_bounds__(256) void pscatter_kernel(const int* __restrict__ src,
                                                       const int* __restrict__ dst,
                                                       int* __restrict__ cnt,
                                                       unsigned* __restrict__ pairs) {
  __shared__ int hist[NBUCKETS];
  __shared__ int base[NBUCKETS];
  int tid = threadIdx.x;
  for (int i = tid; i < NBUCKETS; i += 256) hist[i] = 0;
  __syncthreads();
  int e0 = blockIdx.x * PSC_CHUNK;
  int e1 = min(e0 + PSC_CHUNK, N_EDGES);
  for (int e = e0 + tid; e < e1; e += 256) atomicAdd(&hist[dst[e] >> 9], 1);
  __syncthreads();
  for (int i = tid; i < NBUCKETS; i += 256) {
    int c = hist[i];
    base[i] = c ? atomicAdd(&cnt[i], c) : 0;
    hist[i] = 0;
  }
  __syncthreads();
  for (int e = e0 + tid; e < e1; e += 256) {
    int d = dst[e];
    int b = d >> 9;
    int slot = base[b] + atomicAdd(&hist[b], 1);
    if (slot < PSC_CAP)
      pairs[(size_t)b * PSC_CAP + slot] = ((unsigned)src[e] << 9) | (unsigned)(d & 511);
  }
}

__global__ __launch_bounds__(256) void bscan_kernel(const int* __restrict__ cnt,
                                                    int* __restrict__ boff,
                                                    int* __restrict__ row_ptr) {
  __shared__ int tmp[256];
  int tid = threadIdx.x;
  int c = (tid < NBUCKETS) ? cnt[tid] : 0;
  tmp[tid] = c;
  __syncthreads();
  for (int off = 1; off < 256; off <<= 1) {
    int t = (tid >= off) ? tmp[tid - off] : 0;
    __syncthreads();
    tmp[tid] += t;
    __syncthreads();
  }
  if (tid < NBUCKETS) boff[tid] = tmp[tid] - c;
  if (tid == 0) row_ptr[N_NODES] = N_EDGES;
}

__global__ __launch_bounds__(256) void bbuild_kernel(const unsigned* __restrict__ pairs,
                                                     const int* __restrict__ cnt,
                                                     const int* __restrict__ boff,
                                                     int* __restrict__ row_ptr,
                                                     int* __restrict__ adj) {
  __shared__ unsigned spairs[PSC_CAP];
  __shared__ int h[512];
  __shared__ int cur[512];
  __shared__ int tmp[256];
  int tid = threadIdx.x, b = blockIdx.x;
  int c = min(cnt[b], PSC_CAP);
  int p0 = boff[b];
  const unsigned* gp = pairs + (size_t)b * PSC_CAP;
  for (int p = tid; p < c; p += 256) spairs[p] = gp[p];
  h[tid] = 0;
  h[tid + 256] = 0;
  __syncthreads();
  for (int p = tid; p < c; p += 256) atomicAdd(&h[spairs[p] & 511u], 1);
  __syncthreads();
  int a0 = h[2 * tid], a1 = h[2 * tid + 1];
  int s = a0 + a1;
  tmp[tid] = s;
  __syncthreads();
  for (int off = 1; off < 256; off <<= 1) {
    int t = (tid >= off) ? tmp[tid - off] : 0;
    __syncthreads();
    tmp[tid] += t;
    __syncthreads();
  }
  int excl = tmp[tid] - s;
  int n0 = b << 9;
  if (n0 + 2 * tid < N_NODES) row_ptr[n0 + 2 * tid] = p0 + excl;
  if (n0 + 2 * tid + 1 < N_NODES) row_ptr[n0 + 2 * tid + 1] = p0 + excl + a0;
  cur[2 * tid] = p0 + excl;
  cur[2 * tid + 1] = p0 + excl + a0;
  __syncthreads();
  for (int p = tid; p < c; p += 256) {
    unsigned pr = spairs[p];
    int pos = atomicAdd(&cur[pr & 511u], 1);
    adj[pos] = (int)(pr >> 9);
  }
}

// ---------------------------------------------------------------- gather agg, layer 0
// self from fp32 x; neighbors from fp8 x8 (128 B rows). 16 lanes/node, 8 cols each.
__global__ __launch_bounds__(256) void gather_l0_kernel(
    const float* __restrict__ in, const unsigned char* __restrict__ in8,
    const int* __restrict__ row_ptr, const int* __restrict__ adj,
    unsigned short* __restrict__ agg) {
  int gid = blockIdx.x * 256 + threadIdx.x;
  int n = gid >> 4;
  if (n >= N_NODES) return;
  int c8 = gid & 15;
  float acc[8];
  {
    const float4* p = (const float4*)(in + (size_t)n * 128) + c8 * 2;
    float4 a = p[0], b = p[1];
    acc[0] = a.x; acc[1] = a.y; acc[2] = a.z; acc[3] = a.w;
    acc[4] = b.x; acc[5] = b.y; acc[6] = b.z; acc[7] = b.w;
  }
  auto addu = [&](uint2 u) {
    float f[4];
    fp8x4_to_f32(u.x, f);
    acc[0] += f[0]; acc[1] += f[1]; acc[2] += f[2]; acc[3] += f[3];
    fp8x4_to_f32(u.y, f);
    acc[4] += f[0]; acc[5] += f[1]; acc[6] += f[2]; acc[7] += f[3];
  };
  int beg = row_ptr[n], end = row_ptr[n + 1];
  int k = beg;
  for (; k + 4 <= end; k += 4) {
    int s0 = adj[k], s1 = adj[k + 1], s2 = adj[k + 2], s3 = adj[k + 3];
    uint2 u0 = *(const uint2*)(in8 + (size_t)s0 * 128 + c8 * 8);
    uint2 u1 = *(const uint2*)(in8 + (size_t)s1 * 128 + c8 * 8);
    uint2 u2 = *(const uint2*)(in8 + (size_t)s2 * 128 + c8 * 8);
    uint2 u3 = *(const uint2*)(in8 + (size_t)s3 * 128 + c8 * 8);
    addu(u0); addu(u1); addu(u2); addu(u3);
  }
  for (; k < end; ++k)
    addu(*(const uint2*)(in8 + (size_t)adj[k] * 128 + c8 * 8));
  uint4 o;
  o.x = pack2(acc[0], acc[1]); o.y = pack2(acc[2], acc[3]);
  o.z = pack2(acc[4], acc[5]); o.w = pack2(acc[6], acc[7]);
  ((uint4*)(agg + (size_t)n * 128))[c8] = o;
}

// ---------------------------------------------------------------- gather agg, layers 1/2
// self from bf16 h; neighbors from fp8 h8; BN+ReLU (params from raw stats) on both.
__global__ __launch_bounds__(256) void gather_ln_kernel(
    const unsigned short* __restrict__ in, const unsigned char* __restrict__ in8,
    const float* __restrict__ stats, const float* __restrict__ g,
    const float* __restrict__ be, const int* __restrict__ row_ptr,
    const int* __restrict__ adj, unsigned short* __restrict__ agg) {
  int gid = blockIdx.x * 256 + threadIdx.x;
  int n = gid >> 4;
  if (n >= N_NODES) return;
  int c8 = gid & 15;
  float sc[8], sh[8];
#pragma unroll
  for (int j = 0; j < 8; ++j) {
    int col = c8 * 8 + j;
    float mean = stats[col] * INV_N;
    float var = stats[128 + col] * INV_N - mean * mean;
    float s = g[col] * rsqrtf(var + BN_EPS);
    sc[j] = s;
    sh[j] = be[col] - mean * s;
  }
  float acc[8];
  {
    uint4 u = ((const uint4*)(in + (size_t)n * 128))[c8];
    float f[8];
    bf8_to_f32(u, f);
#pragma unroll
    for (int j = 0; j < 8; ++j) acc[j] = fmaxf(fmaf(f[j], sc[j], sh[j]), 0.f);
  }
  auto addu = [&](uint2 u) {
    float f[4];
    fp8x4_to_f32(u.x, f);
#pragma unroll
    for (int j = 0; j < 4; ++j) acc[j] += fmaxf(fmaf(f[j], sc[j], sh[j]), 0.f);
    fp8x4_to_f32(u.y, f);
#pragma unroll
    for (int j = 0; j < 4; ++j) acc[4 + j] += fmaxf(fmaf(f[j], sc[4 + j], sh[4 + j]), 0.f);
  };
  int beg = row_ptr[n], end = row_ptr[n + 1];
  int k = beg;
  for (; k + 4 <= end; k += 4) {
    int s0 = adj[k], s1 = adj[k + 1], s2 = adj[k + 2], s3 = adj[k + 3];
    uint2 u0 = *(const uint2*)(in8 + (size_t)s0 * 128 + c8 * 8);
    uint2 u1 = *(const uint2*)(in8 + (size_t)s1 * 128 + c8 * 8);
    uint2 u2 = *(const uint2*)(in8 + (size_t)s2 * 128 + c8 * 8);
    uint2 u3 = *(const uint2*)(in8 + (size_t)s3 * 128 + c8 * 8);
    addu(u0); addu(u1); addu(u2); addu(u3);
  }
  for (; k < end; ++k)
    addu(*(const uint2*)(in8 + (size_t)adj[k] * 128 + c8 * 8));
  uint4 o;
  o.x = pack2(acc[0], acc[1]); o.y = pack2(acc[2], acc[3]);
  o.z = pack2(acc[4], acc[5]); o.w = pack2(acc[6], acc[7]);
  ((uint4*)(agg + (size_t)n * 128))[c8] = o;
}

// ---------------------------------------------------------------- fused MLP (R9 best-measured variant)
// GEMM1 (sWa staged) -> per-wave XOR LDS bounce -> GEMM2; O (bf16) + optional O8 (fp8 copy).
template <int N2>
__global__ __launch_bounds__(256) void fused_mlp_kernel(
    const unsigned short* __restrict__ A, const unsigned short* __restrict__ Wfa,
    const unsigned short* __restrict__ Wfb, const float* __restrict__ ba,
    const float* __restrict__ bb, unsigned short* __restrict__ O,
    unsigned char* __restrict__ O8, float* __restrict__ gstats, int M, int ntiles) {
  constexpr int NT2 = N2 / 16;
  __shared__ unsigned short sWa[128 * 128];
  __shared__ unsigned short sH1[4][16 * 128];
  __shared__ float sB[256];
  __shared__ float sSt[2 * N2];

  int tid = threadIdx.x;
  {
    const uint4* s = (const uint4*)Wfa;
    uint4* d = (uint4*)sWa;
    for (int i = tid; i < 128 * 128 / 8; i += 256) d[i] = s[i];
  }
  if (tid < 128) sB[tid] = ba[tid];
  else if (tid - 128 < N2) sB[tid] = bb[tid - 128];
  for (int i = tid; i < 2 * N2; i += 256) sSt[i] = 0.f;
  __syncthreads();

  int lane = tid & 63, wave = tid >> 6;
  int m16 = lane & 15, quad = lane >> 4;
  unsigned short* h1 = &sH1[wave][0];
  const bf16x8* sWa8 = (const bf16x8*)sWa;
  const bf16x8* Wfb8 = (const bf16x8*)Wfb;
  const bool w8 = O8 != nullptr;

  for (int t = blockIdx.x; t < ntiles; t += gridDim.x) {
    int row0 = t * 64 + wave * 16;
    int row = row0 + m16;

    bf16x8 a[4];
    if (row < M) {
      const bf16x8* Ar = (const bf16x8*)(A + (size_t)row * 128);
#pragma unroll
      for (int kc = 0; kc < 4; ++kc) a[kc] = Ar[kc * 4 + quad];
    } else {
#pragma unroll
      for (int kc = 0; kc < 4; ++kc)
#pragma unroll
        for (int j = 0; j < 8; ++j) a[kc][j] = 0;
    }

    f32x4 acc2[NT2];
#pragma unroll
    for (int nt = 0; nt < NT2; ++nt) {
      float bv = sB[128 + nt * 16 + m16];
#pragma unroll
      for (int r = 0; r < 4; ++r) acc2[nt][r] = bv;
    }

#pragma unroll
    for (int kc2 = 0; kc2 < 4; ++kc2) {
      bf16x8 wb[NT2];
#pragma unroll
      for (int nt = 0; nt < NT2; ++nt) wb[nt] = Wfb8[(nt * 4 + kc2) * 64 + lane];

#pragma unroll
      for (int t2 = 0; t2 < 2; ++t2) {
        int n1t = 2 * kc2 + t2;
        float bv = sB[n1t * 16 + m16];
        f32x4 acc1 = {bv, bv, bv, bv};
#pragma unroll
        for (int kc = 0; kc < 4; ++kc)
          acc1 = __builtin_amdgcn_mfma_f32_16x16x32_bf16(
              a[kc], sWa8[(n1t * 4 + kc) * 64 + lane], acc1, 0, 0, 0);
        int n1 = n1t * 16 + m16;
        int c = n1 >> 3;
#pragma unroll
        for (int r = 0; r < 4; ++r) {
          int mrow = quad * 4 + r;
          h1[mrow * 128 + (((c ^ mrow) & 15) << 3) + (n1 & 7)] =
              rne16(fmaxf(acc1[r], 0.f));
        }
      }
      int cR = kc2 * 4 + quad;
      bf16x8 hf = *(const bf16x8*)&h1[m16 * 128 + (((cR ^ m16) & 15) << 3)];
#pragma unroll
      for (int nt = 0; nt < NT2; ++nt)
        acc2[nt] = __builtin_amdgcn_mfma_f32_16x16x32_bf16(hf, wb[nt], acc2[nt], 0, 0, 0);
    }

#pragma unroll
    for (int nt = 0; nt < NT2; ++nt) {
      float s = 0.f, ss = 0.f;
#pragma unroll
      for (int r = 0; r < 4; ++r) {
        int grow = row0 + quad * 4 + r;
        if (grow < M) {
          float v = acc2[nt][r];
          s += v;
          ss += v * v;
          O[(size_t)grow * N2 + nt * 16 + m16] = rne16(v);
          if (w8) O8[(size_t)grow * N2 + nt * 16 + m16] = f32_to_fp8(v);
        }
      }
      atomicAdd(&sSt[nt * 16 + m16], s);
      atomicAdd(&sSt[N2 + nt * 16 + m16], ss);
    }
  }
  __syncthreads();
  for (int i = tid; i < 2 * N2; i += 256) atomicAdd(&gstats[i], sSt[i]);
}

// ---------------------------------------------------------------- segmented mean pool
__global__ __launch_bounds__(256) void pool_seg_kernel(
    const unsigned short* __restrict__ h, const float* __restrict__ stats,
    const float* __restrict__ g, const float* __restrict__ be,
    const int* __restrict__ batch, float* __restrict__ sums) {
  __shared__ float sacc[N_GRAPHS * 64];
  int tid = threadIdx.x;
  for (int i = tid; i < N_GRAPHS * 64; i += 256) sacc[i] = 0.f;

  int base = blockIdx.x * POOL_CHUNK;
  int last = min(base + POOL_CHUNK, N_NODES) - 1;
  int c4 = tid & 15;
  int r = tid >> 4;
  float4 sc, sh;
  {
    float m0 = stats[c4 * 4 + 0] * INV_N, m1 = stats[c4 * 4 + 1] * INV_N;
    float m2 = stats[c4 * 4 + 2] * INV_N, m3 = stats[c4 * 4 + 3] * INV_N;
    sc.x = g[c4 * 4 + 0] * rsqrtf(stats[64 + c4 * 4 + 0] * INV_N - m0 * m0 + BN_EPS);
    sc.y = g[c4 * 4 + 1] * rsqrtf(stats[64 + c4 * 4 + 1] * INV_N - m1 * m1 + BN_EPS);
    sc.z = g[c4 * 4 + 2] * rsqrtf(stats[64 + c4 * 4 + 2] * INV_N - m2 * m2 + BN_EPS);
    sc.w = g[c4 * 4 + 3] * rsqrtf(stats[64 + c4 * 4 + 3] * INV_N - m3 * m3 + BN_EPS);
    sh.x = be[c4 * 4 + 0] - m0 * sc.x;
    sh.y = be[c4 * 4 + 1] - m1 * sc.y;
    sh.z = be[c4 * 4 + 2] - m2 * sc.z;
    sh.w = be[c4 * 4 + 3] - m3 * sc.w;
  }
  __syncthreads();

  float4 acc = make_float4(0.f, 0.f, 0.f, 0.f);
  int gcur = -1;
#pragma unroll 1
  for (int j = 0; j < POOL_CHUNK / 16; ++j) {
    int node = base + j * 16 + r;
    if (node >= N_NODES) break;
    int gg = batch[node];
    if (gg != gcur) {
      if (gcur >= 0) {
        float* p = &sacc[gcur * 64 + c4 * 4];
        atomicAdd(p + 0, acc.x); atomicAdd(p + 1, acc.y);
        atomicAdd(p + 2, acc.z); atomicAdd(p + 3, acc.w);
      }
      gcur = gg;
      acc = make_float4(0.f, 0.f, 0.f, 0.f);
    }
    uint2 u = ((const uint2*)(h + (size_t)node * 64))[c4];
    float f0, f1, f2, f3;
    bf2_to_f32(u.x, f0, f1);
    bf2_to_f32(u.y, f2, f3);
    acc.x += fmaxf(fmaf(f0, sc.x, sh.x), 0.f);
    acc.y += fmaxf(fmaf(f1, sc.y, sh.y), 0.f);
    acc.z += fmaxf(fmaf(f2, sc.z, sh.z), 0.f);
    acc.w += fmaxf(fmaf(f3, sc.w, sh.w), 0.f);
  }
  if (gcur >= 0) {
    float* p = &sacc[gcur * 64 + c4 * 4];
    atomicAdd(p + 0, acc.x); atomicAdd(p + 1, acc.y);
    atomicAdd(p + 2, acc.z); atomicAdd(p + 3, acc.w);
  }
  __syncthreads();

  int gmin = batch[base];
  int gmax = batch[last];
  for (int gg = gmin; gg <= gmax; ++gg)
    for (int i = tid; i < 64; i += 256)
      atomicAdd(&sums[gg * 64 + i], sacc[gg * 64 + i]);
}

// ---------------------------------------------------------------- divide by counts (binary search)
__global__ __launch_bounds__(256) void div_kernel(const float* __restrict__ sums,
                                                  const int* __restrict__ batch,
                                                  float* __restrict__ out) {
  int i = blockIdx.x * blockDim.x + threadIdx.x;
  if (i >= N_GRAPHS * 64) return;
  int g = i >> 6;
  int lo = 0, hi = N_NODES;
  while (lo < hi) { int m = (lo + hi) >> 1; if (batch[m] < g) lo = m + 1; else hi = m; }
  int lb = lo;
  lo = 0; hi = N_NODES;
  while (lo < hi) { int m = (lo + hi) >> 1; if (batch[m] <= g) lo = m + 1; else hi = m; }
  float cnt = (float)(lo - lb);
  out[i] = sums[i] / fmaxf(cnt, 1.0f);
}

// ---------------------------------------------------------------- launch
extern "C" void kernel_launch(void* const* d_in, const int* in_sizes, int n_in,
                              void* d_out, int out_size, void* d_ws, size_t ws_size,
                              hipStream_t stream) {
  const float* x = (const float*)d_in[0];
  const int* edge_index = (const int*)d_in[1];
  const int* batch = (const int*)d_in[2];
  const int* src = edge_index;
  const int* dst = edge_index + N_EDGES;

  const float* wa[3] = {(const float*)d_in[3], (const float*)d_in[9],  (const float*)d_in[15]};
  const float* ba[3] = {(const float*)d_in[4], (const float*)d_in[10], (const float*)d_in[16]};
  const float* wb[3] = {(const float*)d_in[5], (const float*)d_in[11], (const float*)d_in[17]};
  const float* bb[3] = {(const float*)d_in[6], (const float*)d_in[12], (const float*)d_in[18]};
  const float* gg[3] = {(const float*)d_in[7], (const float*)d_in[13], (const float*)d_in[19]};
  const float* be[3] = {(const float*)d_in[8], (const float*)d_in[14], (const float*)d_in[20]};

  // -------- workspace layout --------
  float* stats0 = (float*)d_ws;   // [sum(128)|sumsq(128)|pad(256)]
  float* stats1 = stats0 + 512;
  float* stats2 = stats1 + 512;   // [sum(64)|sumsq(64)|pad(128)]
  float* psums = stats2 + 256;    // 8192
  int* cnt = (int*)(psums + (size_t)N_GRAPHS * 64);  // 256, zeroed with floats
  int* boff = cnt + 256;                              // 256
  int* row_ptr = boff + 256;                          // 100004
  int* adj = row_ptr + 100004;
  unsigned* pairs = (unsigned*)(adj + N_EDGES);       // NBUCKETS*PSC_CAP
  unsigned char* x8 = (unsigned char*)(pairs + (size_t)NBUCKETS * PSC_CAP);  // N*128 fp8
  unsigned char* f8 = x8 + (size_t)N_NODES * 128;                            // N*128 fp8
  unsigned short* b0 = (unsigned short*)(f8 + (size_t)N_NODES * 128);
  unsigned short* b1 = b0 + (size_t)N_NODES * 128;
  unsigned short* wf0 = b1 + (size_t)N_NODES * 128;
  unsigned short* wf[6];
  for (int i = 0; i < 6; ++i) wf[i] = wf0 + (size_t)i * 16384;
  size_t needed = (size_t)((char*)(wf0 + 6 * 16384) - (char*)d_ws);
  if (ws_size < needed) return;

  hipMemsetAsync(stats0, 0, 9472 * 4 + 256 * 4, stream);

  WPArgs wp;
  wp.w[0] = wa[0]; wp.w[1] = wb[0]; wp.w[2] = wa[1];
  wp.w[3] = wb[1]; wp.w[4] = wa[2]; wp.w[5] = wb[2];
  for (int i = 0; i < 6; ++i) wp.o[i] = wf[i];
  wprep_all_kernel<<<352, 256, 0, stream>>>(wp);

  // x -> fp8 copy (neighbor reads)
  f2f8_kernel<<<(N_NODES * 16 + 255) / 256, 256, 0, stream>>>(x, x8, N_NODES * 16);

  pscatter_kernel<<<PSC_BLOCKS, 256, 0, stream>>>(src, dst, cnt, pairs);
  bscan_kernel<<<1, 256, 0, stream>>>(cnt, boff, row_ptr);
  bbuild_kernel<<<NBUCKETS, 256, 0, stream>>>(pairs, cnt, boff, row_ptr, adj);

  const int gather_blocks = (N_NODES * 16 + 255) / 256;
  const int fused_blocks = 768;

  // ---- layer 0: gather(x self, x8 neighbors) -> b0 ; fused MLP b0 -> b1 + f8 (stats0)
  gather_l0_kernel<<<gather_blocks, 256, 0, stream>>>(x, x8, row_ptr, adj, b0);
  fused_mlp_kernel<128><<<fused_blocks, 256, 0, stream>>>(
      b0, wf[0], wf[1], ba[0], bb[0], b1, f8, stats0, N_NODES, MLP_TILES);

  // ---- layer 1: gather(b1 self, f8 neighbors, BN0) -> b0 ; fused MLP b0 -> b1 + f8 (stats1)
  gather_ln_kernel<<<gather_blocks, 256, 0, stream>>>(b1, f8, stats0, gg[0], be[0],
                                                      row_ptr, adj, b0);
  fused_mlp_kernel<128><<<fused_blocks, 256, 0, stream>>>(
      b0, wf[2], wf[3], ba[1], bb[1], b1, f8, stats1, N_NODES, MLP_TILES);

  // ---- layer 2: gather(b1 self, f8 neighbors, BN1) -> b0 ; fused MLP b0 -> b1 (N2=64, stats2)
  gather_ln_kernel<<<gather_blocks, 256, 0, stream>>>(b1, f8, stats1, gg[1], be[1],
                                                      row_ptr, adj, b0);
  fused_mlp_kernel<64><<<fused_blocks, 256, 0, stream>>>(
      b0, wf[4], wf[5], ba[2], bb[2], b1, nullptr, stats2, N_NODES, MLP_TILES);

  // ---- pool (BN2 computed in-kernel) + divide
  pool_seg_kernel<<<POOL_BLOCKS, 256, 0, stream>>>(b1, stats2, gg[2], be[2], batch, psums);
  div_kernel<<<32, 256, 0, stream>>>(psums, batch, (float*)d_out);
}